// Round 10
// baseline (182.980 us; speedup 1.0000x reference)
//
#include <hip/hip_runtime.h>

typedef __bf16 bf16;
typedef __attribute__((ext_vector_type(4))) __bf16 bf16x4;
typedef __attribute__((ext_vector_type(8))) __bf16 bf16x8;
typedef __attribute__((ext_vector_type(4))) float f32x4;
typedef __attribute__((ext_vector_type(16))) float f32x16;
typedef unsigned int u32;

#define D_MODEL 1024
#define SEQ_L   2048
#define NHEAD   16
#define HDIM    64
#define MROWS   4096   // B*L

// ---- workspace layout (bf16-element offsets) ----
#define FEAT_OFF  512u
#define WQ_OFF    (FEAT_OFF + 4194304u)
#define WK_OFF    (WQ_OFF + 1048576u)
#define WV_OFF    (WK_OFF + 1048576u)
#define BQ_OFF    (WV_OFF + 1048576u)
#define BK_OFF    (BQ_OFF + 1024u)
#define BV_OFF    (BK_OFF + 1024u)
#define Q_OFF     (BV_OFF + 1024u)
#define K_OFF     (Q_OFF + 4194304u)
#define V_OFF     (K_OFF + 4194304u)     // z=2 writes Vt here: [b][dout(1024)][token(2048)]
// After qkv_gemm, FEAT/W regions are dead -> reused by attention partials:
//   O1 (bf16, 4096x1024) at FEAT_OFF ; L (f32 [2][32][2048]) at WQ_OFF

// async global->LDS, 16B per lane; LDS dest = wave-uniform base + lane*16
typedef const __attribute__((address_space(1))) u32* gp_t;
typedef __attribute__((address_space(3))) u32* lp_t;
__device__ __forceinline__ void ld16(const bf16* g, bf16* l) {
    __builtin_amdgcn_global_load_lds((gp_t)g, (lp_t)l, 16, 0, 0);
}

// ---------------------------------------------------------------------------
// Convert f32 inputs -> bf16 in ws. Flat grid: 7171 blocks x 256 thr x 4 elems.
// ---------------------------------------------------------------------------
__global__ void convert_in(const float* __restrict__ feat,
                           const float* __restrict__ wq, const float* __restrict__ wk,
                           const float* __restrict__ wv,
                           const float* __restrict__ bq, const float* __restrict__ bk,
                           const float* __restrict__ bv,
                           bf16* __restrict__ ws) {
    const int bid = blockIdx.x;
    const float* src; bf16* dst; int off;
    if (bid < 4096)      { src = feat; dst = ws + FEAT_OFF; off = bid * 1024; }
    else if (bid < 5120) { src = wq;   dst = ws + WQ_OFF;   off = (bid - 4096) * 1024; }
    else if (bid < 6144) { src = wk;   dst = ws + WK_OFF;   off = (bid - 5120) * 1024; }
    else if (bid < 7168) { src = wv;   dst = ws + WV_OFF;   off = (bid - 6144) * 1024; }
    else if (bid == 7168){ src = bq;   dst = ws + BQ_OFF;   off = 0; }
    else if (bid == 7169){ src = bk;   dst = ws + BK_OFF;   off = 0; }
    else                 { src = bv;   dst = ws + BV_OFF;   off = 0; }
    int idx = off + threadIdx.x * 4;
    float4 v = *(const float4*)(src + idx);
    dst[idx + 0] = (bf16)v.x;
    dst[idx + 1] = (bf16)v.y;
    dst[idx + 2] = (bf16)v.z;
    dst[idx + 3] = (bf16)v.w;
}

// ---------------------------------------------------------------------------
// QKV projection, m97 recipe. z=0: Q=X*Wq^T  z=1: K=X*Wk^T (masked rows
// ZEROED)  z=2: Vt = Wv*X^T transposed epilogue (masked token-cols ZEROED).
// Zeroing masked K rows / Vt cols makes attention masking implicit:
// st=0 -> p=exp(0)=1, PV contribution 0; l corrected by popcount in attn.
// ---------------------------------------------------------------------------
__global__ __launch_bounds__(256, 2) void qkv_gemm(const bf16* __restrict__ ws,
                                                   bf16* __restrict__ wsw,
                                                   const int* __restrict__ mask) {
    const int zi = blockIdx.z;
    const bf16* Amat = (zi == 2) ? ws + WV_OFF : ws + FEAT_OFF;
    const bf16* Bmat = (zi == 0) ? ws + WQ_OFF : (zi == 1) ? ws + WK_OFF : ws + FEAT_OFF;
    const bf16* bias = ws + ((zi == 0) ? BQ_OFF : (zi == 1) ? BK_OFF : BV_OFF);
    bf16* Y = (zi == 2) ? wsw + V_OFF : wsw + Q_OFF + (size_t)zi * 4194304u;

    __shared__ bf16 Alds[128 * 64];
    __shared__ bf16 Blds[128 * 64];

    const int t    = threadIdx.x;
    const int lane = t & 63;
    const int wave = t >> 6;
    const int quad = lane >> 4;
    const int l16  = lane & 15;
    const int m0   = ((zi == 2) ? blockIdx.y : blockIdx.x) * 128;
    const int n0   = ((zi == 2) ? blockIdx.x : blockIdx.y) * 128;
    const int wrow = (wave >> 1) * 64;
    const int wcol = (wave & 1) * 64;

    const int r8 = lane >> 3;
    const int sl = lane & 7;
    const int sg = sl ^ r8;

    f32x4 acc[4][4];
    for (int mi = 0; mi < 4; ++mi)
        for (int ni = 0; ni < 4; ++ni)
            acc[mi][ni] = (f32x4){0.f, 0.f, 0.f, 0.f};

    for (int k0 = 0; k0 < D_MODEL; k0 += 64) {
#pragma unroll
        for (int i = 0; i < 4; ++i) {
            int ch  = wave * 4 + i;
            int row = ch * 8 + r8;
            ld16(Amat + (size_t)(m0 + row) * D_MODEL + k0 + sg * 8, Alds + ch * 512);
            ld16(Bmat + (size_t)(n0 + row) * D_MODEL + k0 + sg * 8, Blds + ch * 512);
        }
        __syncthreads();

#pragma unroll
        for (int kk = 0; kk < 2; ++kk) {
            const int sgb = quad + kk * 4;
            bf16x8 af[4], bfr[4];
#pragma unroll
            for (int mi = 0; mi < 4; ++mi) {
                int row = wrow + mi * 16 + l16;
                af[mi] = *(const bf16x8*)(&Alds[row * 64 + ((sgb ^ (row & 7)) << 3)]);
            }
#pragma unroll
            for (int ni = 0; ni < 4; ++ni) {
                int row = wcol + ni * 16 + l16;
                bfr[ni] = *(const bf16x8*)(&Blds[row * 64 + ((sgb ^ (row & 7)) << 3)]);
            }
#pragma unroll
            for (int mi = 0; mi < 4; ++mi)
#pragma unroll
                for (int ni = 0; ni < 4; ++ni)
                    acc[mi][ni] = __builtin_amdgcn_mfma_f32_16x16x32_bf16(
                        af[mi], bfr[ni], acc[mi][ni], 0, 0, 0);
        }
        __syncthreads();
    }

    if (zi < 2) {
#pragma unroll
        for (int ni = 0; ni < 4; ++ni) {
            int col = n0 + wcol + ni * 16 + l16;
            float bvf = (float)bias[col];
#pragma unroll
            for (int mi = 0; mi < 4; ++mi) {
                int rowb = m0 + wrow + mi * 16 + quad * 4;
#pragma unroll
                for (int r = 0; r < 4; ++r) {
                    float v = acc[mi][ni][r] + bvf;
                    if (zi == 1 && mask[rowb + r] == 0) v = 0.f;   // zero masked K rows
                    Y[(size_t)(rowb + r) * D_MODEL + col] = (bf16)v;
                }
            }
        }
    } else {
#pragma unroll
        for (int mi = 0; mi < 4; ++mi) {
#pragma unroll
            for (int r = 0; r < 4; ++r) {
                int rowv = m0 + wrow + mi * 16 + quad * 4 + r;   // dout
                float bvf = (float)bias[rowv];
#pragma unroll
                for (int ni = 0; ni < 4; ++ni) {
                    int col = n0 + wcol + ni * 16 + l16;          // token
                    float v = acc[mi][ni][r] + bvf;
                    if (mask[col] == 0) v = 0.f;                  // zero masked Vt cols
                    size_t addr = (size_t)(col >> 11) * 2097152u +
                                  (size_t)rowv * 2048u + (col & 2047);
                    Y[addr] = (bf16)v;
                }
            }
        }
    }
}

// ---------------------------------------------------------------------------
// Flash attention v7: implicit masking (K rows / Vt cols pre-zeroed),
// S^T formulation, 32x32x16 MFMA, max-free softmax, key-split z=2,
// P in registers. l corrected by popcount of unmasked keys.
// grid (bh, qt, ks2) = (32, 32, 2) -> 4096 waves = 16 waves/CU.
// ---------------------------------------------------------------------------
__global__ __launch_bounds__(128, 4) void attn_kernel(
    const bf16* __restrict__ ws, bf16* __restrict__ wsw,
    const int* __restrict__ mask, float* __restrict__ out) {
    const int bh  = blockIdx.x;          // 0..31
    const int qt  = blockIdx.y;          // 0..31 (64 q-rows per block)
    const int ks2 = blockIdx.z;          // key split 0/1
    const int b   = bh >> 4, h = bh & 15;
    const int t    = threadIdx.x;
    const int lane = t & 63;
    const int wave = t >> 6;            // 0..1
    const int half = lane >> 5;
    const int l31  = lane & 31;
    const int kt0  = ks2 * 1024;

    __shared__ bf16 Klds[64 * 64];            // [key][d], seg-swizzled
    __shared__ bf16 Vlds[64 * 64];            // [d][key], seg-swizzled

    const bf16* Qh  = ws + Q_OFF + (size_t)(b * SEQ_L) * D_MODEL + h * HDIM;
    const bf16* Kh  = ws + K_OFF + (size_t)(b * SEQ_L) * D_MODEL + h * HDIM;
    const bf16* Vth = ws + V_OFF + (size_t)b * 2097152u + (size_t)(h * HDIM) * SEQ_L;

    // Q fragments as B-operand (n=q=l31, k=d), pre-scaled by 0.125 (exact).
    const int qrow0 = qt * 64 + wave * 32;
    bf16x8 qf[4];
#pragma unroll
    for (int ks = 0; ks < 4; ++ks) {
        qf[ks] = *(const bf16x8*)(Qh + (size_t)(qrow0 + l31) * D_MODEL
                                  + ks * 16 + half * 8);
#pragma unroll
        for (int j = 0; j < 8; ++j)
            qf[ks][j] = (bf16)((float)qf[ks][j] * 0.125f);
    }

    f32x16 o[2];
    float lsum = 0.f;
    int nm = 0;                               // unmasked-key count
#pragma unroll
    for (int dt = 0; dt < 2; ++dt)
#pragma unroll
        for (int i = 0; i < 16; ++i) o[dt][i] = 0.f;

    // staging geometry: per iter i, wave w covers rows i*16 + w*8 + (lane>>3)
    const int srow = (lane >> 3);            // 0..7
    const int sg   = (lane & 7) ^ srow;      // swizzled global segment

    for (int kt = kt0; kt < kt0 + 1024; kt += 64) {
        // ---- async stage K [key][d] and Vt [d][key], swizzled
#pragma unroll
        for (int i = 0; i < 4; ++i) {
            int row = i * 16 + wave * 8 + srow;
            ld16(Kh + (size_t)(kt + row) * D_MODEL + sg * 8,
                 Klds + i * 1024 + wave * 512);
            ld16(Vth + (size_t)row * SEQ_L + kt + sg * 8,
                 Vlds + i * 1024 + wave * 512);
        }
        int mv = mask[b * SEQ_L + kt + lane];
        nm += (int)__popcll(__ballot(mv != 0));
        __syncthreads();    // drains ld16 + joins waves

        // ---- S^T = K * Q^T : D[key-rows][q-cols]
        f32x16 st[2];
#pragma unroll
        for (int ktile = 0; ktile < 2; ++ktile) {
#pragma unroll
            for (int i = 0; i < 16; ++i) st[ktile][i] = 0.f;
#pragma unroll
            for (int ks = 0; ks < 4; ++ks) {
                const int row  = ktile * 32 + l31;
                const int slot = (ks * 2 + half) ^ (l31 & 7);
                bf16x8 kf = *(const bf16x8*)(&Klds[row * 64 + slot * 8]);
                st[ktile] = __builtin_amdgcn_mfma_f32_32x32x16_bf16(
                    kf, qf[ks], st[ktile], 0, 0, 0);
            }
        }

        // ---- P = exp(S^T); masked keys give st=0 -> p=1 (corrected in l)
        bf16x4 pk[2][4];
#pragma unroll
        for (int ktile = 0; ktile < 2; ++ktile) {
#pragma unroll
            for (int g = 0; g < 4; ++g) {
                bf16x4 pkv;
#pragma unroll
                for (int j = 0; j < 4; ++j) {
                    float p = __expf(st[ktile][g * 4 + j]);
                    lsum += p;
                    pkv[j] = (bf16)p;
                }
                pk[ktile][g] = pkv;
            }
        }

        // ---- C->A layout via one shfl_xor(32) per fragment
        bf16x8 pf[4];
#pragma unroll
        for (int ks = 0; ks < 4; ++ks) {
            const int k1 = ks & 1, kt2 = ks >> 1;
            uint2 a  = __builtin_bit_cast(uint2, pk[kt2][2 * k1]);
            uint2 bb = __builtin_bit_cast(uint2, pk[kt2][2 * k1 + 1]);
            uint2 keep, send;
            keep.x = half ? bb.x : a.x;  keep.y = half ? bb.y : a.y;
            send.x = half ? a.x : bb.x;  send.y = half ? a.y : bb.y;
            uint2 recv;
            recv.x = (unsigned)__shfl_xor((int)send.x, 32);
            recv.y = (unsigned)__shfl_xor((int)send.y, 32);
            uint4 frag;
            frag.x = half ? recv.x : keep.x;
            frag.y = half ? recv.y : keep.y;
            frag.z = half ? keep.x : recv.x;
            frag.w = half ? keep.y : recv.y;
            pf[ks] = __builtin_bit_cast(bf16x8, frag);
        }

        // ---- O += P * V  (masked Vt cols are zero -> p=1 adds nothing)
#pragma unroll
        for (int dt = 0; dt < 2; ++dt) {
#pragma unroll
            for (int ks = 0; ks < 4; ++ks) {
                const int row  = dt * 32 + l31;
                const int slot = (ks * 2 + half) ^ (l31 & 7);
                bf16x8 vf = *(const bf16x8*)(&Vlds[row * 64 + slot * 8]);
                o[dt] = __builtin_amdgcn_mfma_f32_32x32x16_bf16(
                    pf[ks], vf, o[dt], 0, 0, 0);
            }
        }
        __syncthreads();
    }

    // ---- export partials; subtract masked-key overcount (exact integer)
    float* Lp  = (float*)(wsw + WQ_OFF);          // [2][32][2048]
    bf16*  O1  = wsw + FEAT_OFF;                  // [4096][1024]
    float l = lsum + __shfl_xor(lsum, 32) - (float)(1024 - nm);
    if (half == 0)
        Lp[ks2 * 65536 + bh * 2048 + qrow0 + l31] = l;
#pragma unroll
    for (int r = 0; r < 16; ++r) {
        const int q32 = (r & 3) + 8 * (r >> 2) + 4 * half;
        const int q = qrow0 + q32;
        const size_t base = ((size_t)(b * SEQ_L + q)) * D_MODEL + h * HDIM;
        if (ks2 == 0) {
            out[base + l31]      = o[0][r];
            out[base + 32 + l31] = o[1][r];
        } else {
            O1[base + l31]      = (bf16)o[0][r];
            O1[base + 32 + l31] = (bf16)o[1][r];
        }
    }
}

// ---------------------------------------------------------------------------
// Combine key-split partials: out = (o0 + o1) / (l0 + l1)
// ---------------------------------------------------------------------------
__global__ void combine(float* __restrict__ out, const bf16* __restrict__ ws) {
    const float* Lp = (const float*)(ws + WQ_OFF);
    const bf16*  O1 = ws + FEAT_OFF;
    int idx = (blockIdx.x * 256 + threadIdx.x) * 4;   // over 4096*1024
    int row = idx >> 10;          // b*2048 + q
    int col = idx & 1023;         // h*64 + dh
    int b = row >> 11, q = row & 2047, h = col >> 6;
    int li = (b * 16 + h) * 2048 + q;
    float rl = 1.0f / fmaxf(Lp[li] + Lp[65536 + li], 1e-30f);
    float4 o0 = *(float4*)(out + idx);
    bf16x4 o1 = *(const bf16x4*)(O1 + idx);
    float4 res;
    res.x = (o0.x + (float)o1[0]) * rl;
    res.y = (o0.y + (float)o1[1]) * rl;
    res.z = (o0.z + (float)o1[2]) * rl;
    res.w = (o0.w + (float)o1[3]) * rl;
    *(float4*)(out + idx) = res;
}

extern "C" void kernel_launch(void* const* d_in, const int* in_sizes, int n_in,
                              void* d_out, int out_size, void* d_ws, size_t ws_size,
                              hipStream_t stream) {
    const float* feat = (const float*)d_in[0];
    const int*   mask = (const int*)d_in[1];
    const float* Wq = (const float*)d_in[2];
    const float* bq = (const float*)d_in[3];
    const float* Wk = (const float*)d_in[4];
    const float* bk = (const float*)d_in[5];
    const float* Wv = (const float*)d_in[6];
    const float* bv = (const float*)d_in[7];

    bf16* ws = (bf16*)d_ws;

    convert_in<<<7171, 256, 0, stream>>>(feat, Wq, Wk, Wv, bq, bk, bv, ws);

    dim3 g1(32, 8, 3);
    qkv_gemm<<<g1, 256, 0, stream>>>(ws, ws, mask);

    dim3 g2(2 * NHEAD, SEQ_L / 64, 2);
    attn_kernel<<<g2, 128, 0, stream>>>(ws, ws, mask, (float*)d_out);

    combine<<<4096, 256, 0, stream>>>((float*)d_out, ws);
}

// Round 11
// 177.321 us; speedup vs baseline: 1.0319x; 1.0319x over previous
//
#include <hip/hip_runtime.h>

typedef __bf16 bf16;
typedef __attribute__((ext_vector_type(4))) __bf16 bf16x4;
typedef __attribute__((ext_vector_type(8))) __bf16 bf16x8;
typedef __attribute__((ext_vector_type(4))) float f32x4;
typedef __attribute__((ext_vector_type(16))) float f32x16;
typedef unsigned int u32;

#define D_MODEL 1024
#define SEQ_L   2048
#define NHEAD   16
#define HDIM    64
#define MROWS   4096   // B*L

// 1/sqrt(64) * log2(e): folded into Wq/bq so attn can use raw v_exp_f32 (exp2)
#define S_SCALE 0.18033688f

// ---- workspace layout (bf16-element offsets) ----
#define FEAT_OFF  512u
#define WQ_OFF    (FEAT_OFF + 4194304u)
#define WK_OFF    (WQ_OFF + 1048576u)
#define WV_OFF    (WK_OFF + 1048576u)
#define BQ_OFF    (WV_OFF + 1048576u)
#define BK_OFF    (BQ_OFF + 1024u)
#define BV_OFF    (BK_OFF + 1024u)
#define Q_OFF     (BV_OFF + 1024u)
#define K_OFF     (Q_OFF + 4194304u)
#define V_OFF     (K_OFF + 4194304u)     // z=2 writes Vt here: [b][dout(1024)][token(2048)]
// After qkv_gemm, FEAT/W regions are dead -> reused by attention partials:
//   O1 (bf16, 4096x1024) at FEAT_OFF ; L (f32 [2][32][2048]) at WQ_OFF

// async global->LDS, 16B per lane; LDS dest = wave-uniform base + lane*16
typedef const __attribute__((address_space(1))) u32* gp_t;
typedef __attribute__((address_space(3))) u32* lp_t;
__device__ __forceinline__ void ld16(const bf16* g, bf16* l) {
    __builtin_amdgcn_global_load_lds((gp_t)g, (lp_t)l, 16, 0, 0);
}

// ---------------------------------------------------------------------------
// Convert f32 inputs -> bf16 in ws. Wq/bq pre-scaled by S_SCALE (exact-count
// rounding: one f32->bf16 round either way). Flat grid: 7171 x 256 x 4.
// ---------------------------------------------------------------------------
__global__ void convert_in(const float* __restrict__ feat,
                           const float* __restrict__ wq, const float* __restrict__ wk,
                           const float* __restrict__ wv,
                           const float* __restrict__ bq, const float* __restrict__ bk,
                           const float* __restrict__ bv,
                           bf16* __restrict__ ws) {
    const int bid = blockIdx.x;
    const float* src; bf16* dst; int off; float sc = 1.0f;
    if (bid < 4096)      { src = feat; dst = ws + FEAT_OFF; off = bid * 1024; }
    else if (bid < 5120) { src = wq;   dst = ws + WQ_OFF;   off = (bid - 4096) * 1024; sc = S_SCALE; }
    else if (bid < 6144) { src = wk;   dst = ws + WK_OFF;   off = (bid - 5120) * 1024; }
    else if (bid < 7168) { src = wv;   dst = ws + WV_OFF;   off = (bid - 6144) * 1024; }
    else if (bid == 7168){ src = bq;   dst = ws + BQ_OFF;   off = 0; sc = S_SCALE; }
    else if (bid == 7169){ src = bk;   dst = ws + BK_OFF;   off = 0; }
    else                 { src = bv;   dst = ws + BV_OFF;   off = 0; }
    int idx = off + threadIdx.x * 4;
    float4 v = *(const float4*)(src + idx);
    dst[idx + 0] = (bf16)(v.x * sc);
    dst[idx + 1] = (bf16)(v.y * sc);
    dst[idx + 2] = (bf16)(v.z * sc);
    dst[idx + 3] = (bf16)(v.w * sc);
}

// ---------------------------------------------------------------------------
// QKV projection, m97 recipe. z=0: Q=X*Wq'^T (Wq pre-scaled)  z=1: K=X*Wk^T
// (masked rows ZEROED)  z=2: Vt = Wv*X^T transposed (masked cols ZEROED).
// ---------------------------------------------------------------------------
__global__ __launch_bounds__(256, 2) void qkv_gemm(const bf16* __restrict__ ws,
                                                   bf16* __restrict__ wsw,
                                                   const int* __restrict__ mask) {
    const int zi = blockIdx.z;
    const bf16* Amat = (zi == 2) ? ws + WV_OFF : ws + FEAT_OFF;
    const bf16* Bmat = (zi == 0) ? ws + WQ_OFF : (zi == 1) ? ws + WK_OFF : ws + FEAT_OFF;
    const bf16* bias = ws + ((zi == 0) ? BQ_OFF : (zi == 1) ? BK_OFF : BV_OFF);
    bf16* Y = (zi == 2) ? wsw + V_OFF : wsw + Q_OFF + (size_t)zi * 4194304u;

    __shared__ bf16 Alds[128 * 64];
    __shared__ bf16 Blds[128 * 64];

    const int t    = threadIdx.x;
    const int lane = t & 63;
    const int wave = t >> 6;
    const int quad = lane >> 4;
    const int l16  = lane & 15;
    const int m0   = ((zi == 2) ? blockIdx.y : blockIdx.x) * 128;
    const int n0   = ((zi == 2) ? blockIdx.x : blockIdx.y) * 128;
    const int wrow = (wave >> 1) * 64;
    const int wcol = (wave & 1) * 64;

    const int r8 = lane >> 3;
    const int sl = lane & 7;
    const int sg = sl ^ r8;

    f32x4 acc[4][4];
    for (int mi = 0; mi < 4; ++mi)
        for (int ni = 0; ni < 4; ++ni)
            acc[mi][ni] = (f32x4){0.f, 0.f, 0.f, 0.f};

    for (int k0 = 0; k0 < D_MODEL; k0 += 64) {
#pragma unroll
        for (int i = 0; i < 4; ++i) {
            int ch  = wave * 4 + i;
            int row = ch * 8 + r8;
            ld16(Amat + (size_t)(m0 + row) * D_MODEL + k0 + sg * 8, Alds + ch * 512);
            ld16(Bmat + (size_t)(n0 + row) * D_MODEL + k0 + sg * 8, Blds + ch * 512);
        }
        __syncthreads();

#pragma unroll
        for (int kk = 0; kk < 2; ++kk) {
            const int sgb = quad + kk * 4;
            bf16x8 af[4], bfr[4];
#pragma unroll
            for (int mi = 0; mi < 4; ++mi) {
                int row = wrow + mi * 16 + l16;
                af[mi] = *(const bf16x8*)(&Alds[row * 64 + ((sgb ^ (row & 7)) << 3)]);
            }
#pragma unroll
            for (int ni = 0; ni < 4; ++ni) {
                int row = wcol + ni * 16 + l16;
                bfr[ni] = *(const bf16x8*)(&Blds[row * 64 + ((sgb ^ (row & 7)) << 3)]);
            }
#pragma unroll
            for (int mi = 0; mi < 4; ++mi)
#pragma unroll
                for (int ni = 0; ni < 4; ++ni)
                    acc[mi][ni] = __builtin_amdgcn_mfma_f32_16x16x32_bf16(
                        af[mi], bfr[ni], acc[mi][ni], 0, 0, 0);
        }
        __syncthreads();
    }

    if (zi < 2) {
#pragma unroll
        for (int ni = 0; ni < 4; ++ni) {
            int col = n0 + wcol + ni * 16 + l16;
            float bvf = (float)bias[col];
#pragma unroll
            for (int mi = 0; mi < 4; ++mi) {
                int rowb = m0 + wrow + mi * 16 + quad * 4;
#pragma unroll
                for (int r = 0; r < 4; ++r) {
                    float v = acc[mi][ni][r] + bvf;
                    if (zi == 1 && mask[rowb + r] == 0) v = 0.f;   // zero masked K rows
                    Y[(size_t)(rowb + r) * D_MODEL + col] = (bf16)v;
                }
            }
        }
    } else {
#pragma unroll
        for (int mi = 0; mi < 4; ++mi) {
#pragma unroll
            for (int r = 0; r < 4; ++r) {
                int rowv = m0 + wrow + mi * 16 + quad * 4 + r;   // dout
                float bvf = (float)bias[rowv];
#pragma unroll
                for (int ni = 0; ni < 4; ++ni) {
                    int col = n0 + wcol + ni * 16 + l16;          // token
                    float v = acc[mi][ni][r] + bvf;
                    if (mask[col] == 0) v = 0.f;                  // zero masked Vt cols
                    size_t addr = (size_t)(col >> 11) * 2097152u +
                                  (size_t)rowv * 2048u + (col & 2047);
                    Y[addr] = (bf16)v;
                }
            }
        }
    }
}

// ---------------------------------------------------------------------------
// Flash attention v8: implicit masking, exp2 (scale pre-folded into Q),
// MFMA row-sum (l via ones-B MFMA), S^T form, key-split z=2, P in registers.
// grid (bh, qt, ks2) = (32, 32, 2) -> 4096 waves = 16 waves/CU.
// ---------------------------------------------------------------------------
__global__ __launch_bounds__(128, 4) void attn_kernel(
    const bf16* __restrict__ ws, bf16* __restrict__ wsw,
    const int* __restrict__ mask, float* __restrict__ out) {
    const int bh  = blockIdx.x;          // 0..31
    const int qt  = blockIdx.y;          // 0..31 (64 q-rows per block)
    const int ks2 = blockIdx.z;          // key split 0/1
    const int b   = bh >> 4, h = bh & 15;
    const int t    = threadIdx.x;
    const int lane = t & 63;
    const int wave = t >> 6;            // 0..1
    const int half = lane >> 5;
    const int l31  = lane & 31;
    const int kt0  = ks2 * 1024;

    __shared__ bf16 Klds[64 * 64];            // [key][d], seg-swizzled
    __shared__ bf16 Vlds[64 * 64];            // [d][key], seg-swizzled

    const bf16* Qh  = ws + Q_OFF + (size_t)(b * SEQ_L) * D_MODEL + h * HDIM;
    const bf16* Kh  = ws + K_OFF + (size_t)(b * SEQ_L) * D_MODEL + h * HDIM;
    const bf16* Vth = ws + V_OFF + (size_t)b * 2097152u + (size_t)(h * HDIM) * SEQ_L;

    // Q fragments as B-operand (n=q=l31, k=d); scale already folded into Wq.
    const int qrow0 = qt * 64 + wave * 32;
    bf16x8 qf[4];
#pragma unroll
    for (int ks = 0; ks < 4; ++ks)
        qf[ks] = *(const bf16x8*)(Qh + (size_t)(qrow0 + l31) * D_MODEL
                                  + ks * 16 + half * 8);

    bf16x8 ones;
#pragma unroll
    for (int j = 0; j < 8; ++j) ones[j] = (bf16)1.0f;

    f32x16 o[2], lacc;
    int nm = 0;                               // unmasked-key count
#pragma unroll
    for (int i = 0; i < 16; ++i) { o[0][i] = 0.f; o[1][i] = 0.f; lacc[i] = 0.f; }

    // staging geometry: per iter i, wave w covers rows i*16 + w*8 + (lane>>3)
    const int srow = (lane >> 3);            // 0..7
    const int sg   = (lane & 7) ^ srow;      // swizzled global segment

    for (int kt = kt0; kt < kt0 + 1024; kt += 64) {
        // ---- async stage K [key][d] and Vt [d][key], swizzled
#pragma unroll
        for (int i = 0; i < 4; ++i) {
            int row = i * 16 + wave * 8 + srow;
            ld16(Kh + (size_t)(kt + row) * D_MODEL + sg * 8,
                 Klds + i * 1024 + wave * 512);
            ld16(Vth + (size_t)row * SEQ_L + kt + sg * 8,
                 Vlds + i * 1024 + wave * 512);
        }
        int mv = mask[b * SEQ_L + kt + lane];
        nm += (int)__popcll(__ballot(mv != 0));
        __syncthreads();    // drains ld16 + joins waves

        // ---- S^T = K * Q^T : D[key-rows][q-cols]  (Q pre-scaled)
        f32x16 st[2];
#pragma unroll
        for (int ktile = 0; ktile < 2; ++ktile) {
#pragma unroll
            for (int i = 0; i < 16; ++i) st[ktile][i] = 0.f;
#pragma unroll
            for (int ks = 0; ks < 4; ++ks) {
                const int row  = ktile * 32 + l31;
                const int slot = (ks * 2 + half) ^ (l31 & 7);
                bf16x8 kf = *(const bf16x8*)(&Klds[row * 64 + slot * 8]);
                st[ktile] = __builtin_amdgcn_mfma_f32_32x32x16_bf16(
                    kf, qf[ks], st[ktile], 0, 0, 0);
            }
        }

        // ---- P = exp2(S^T); masked keys give st=0 -> p=1 (corrected in l)
        bf16x4 pk[2][4];
#pragma unroll
        for (int ktile = 0; ktile < 2; ++ktile) {
#pragma unroll
            for (int g = 0; g < 4; ++g) {
                bf16x4 pkv;
#pragma unroll
                for (int j = 0; j < 4; ++j)
                    pkv[j] = (bf16)__builtin_amdgcn_exp2f(st[ktile][g * 4 + j]);
                pk[ktile][g] = pkv;
            }
        }

        // ---- C->A layout via one shfl_xor(32) per fragment
        bf16x8 pf[4];
#pragma unroll
        for (int ks = 0; ks < 4; ++ks) {
            const int k1 = ks & 1, kt2 = ks >> 1;
            uint2 a  = __builtin_bit_cast(uint2, pk[kt2][2 * k1]);
            uint2 bb = __builtin_bit_cast(uint2, pk[kt2][2 * k1 + 1]);
            uint2 keep, send;
            keep.x = half ? bb.x : a.x;  keep.y = half ? bb.y : a.y;
            send.x = half ? a.x : bb.x;  send.y = half ? a.y : bb.y;
            uint2 recv;
            recv.x = (unsigned)__shfl_xor((int)send.x, 32);
            recv.y = (unsigned)__shfl_xor((int)send.y, 32);
            uint4 frag;
            frag.x = half ? recv.x : keep.x;
            frag.y = half ? recv.y : keep.y;
            frag.z = half ? keep.x : recv.x;
            frag.w = half ? keep.y : recv.y;
            pf[ks] = __builtin_bit_cast(bf16x8, frag);
        }

        // ---- O += P * V ; l += P * ones (row-sums on the MFMA pipe)
#pragma unroll
        for (int ks = 0; ks < 4; ++ks)
            lacc = __builtin_amdgcn_mfma_f32_32x32x16_bf16(pf[ks], ones, lacc, 0, 0, 0);
#pragma unroll
        for (int dt = 0; dt < 2; ++dt) {
#pragma unroll
            for (int ks = 0; ks < 4; ++ks) {
                const int row  = dt * 32 + l31;
                const int slot = (ks * 2 + half) ^ (l31 & 7);
                bf16x8 vf = *(const bf16x8*)(&Vlds[row * 64 + slot * 8]);
                o[dt] = __builtin_amdgcn_mfma_f32_32x32x16_bf16(
                    pf[ks], vf, o[dt], 0, 0, 0);
            }
        }
        __syncthreads();
    }

    // ---- export partials; lacc C-layout row = q32 (all cols identical);
    //      subtract masked-key overcount (exact integer)
    float* Lp  = (float*)(wsw + WQ_OFF);          // [2][32][2048]
    bf16*  O1  = wsw + FEAT_OFF;                  // [4096][1024]
    const float corr = (float)(1024 - nm);
#pragma unroll
    for (int r = 0; r < 16; ++r) {
        const int q32 = (r & 3) + 8 * (r >> 2) + 4 * half;
        const int q = qrow0 + q32;
        const size_t base = ((size_t)(b * SEQ_L + q)) * D_MODEL + h * HDIM;
        if (l31 == 0)
            Lp[ks2 * 65536 + bh * 2048 + qrow0 + q32] = lacc[r] - corr;
        if (ks2 == 0) {
            out[base + l31]      = o[0][r];
            out[base + 32 + l31] = o[1][r];
        } else {
            O1[base + l31]      = (bf16)o[0][r];
            O1[base + 32 + l31] = (bf16)o[1][r];
        }
    }
}

// ---------------------------------------------------------------------------
// Combine key-split partials: out = (o0 + o1) / (l0 + l1)
// ---------------------------------------------------------------------------
__global__ void combine(float* __restrict__ out, const bf16* __restrict__ ws) {
    const float* Lp = (const float*)(ws + WQ_OFF);
    const bf16*  O1 = ws + FEAT_OFF;
    int idx = (blockIdx.x * 256 + threadIdx.x) * 4;   // over 4096*1024
    int row = idx >> 10;          // b*2048 + q
    int col = idx & 1023;         // h*64 + dh
    int b = row >> 11, q = row & 2047, h = col >> 6;
    int li = (b * 16 + h) * 2048 + q;
    float rl = 1.0f / fmaxf(Lp[li] + Lp[65536 + li], 1e-30f);
    float4 o0 = *(float4*)(out + idx);
    bf16x4 o1 = *(const bf16x4*)(O1 + idx);
    float4 res;
    res.x = (o0.x + (float)o1[0]) * rl;
    res.y = (o0.y + (float)o1[1]) * rl;
    res.z = (o0.z + (float)o1[2]) * rl;
    res.w = (o0.w + (float)o1[3]) * rl;
    *(float4*)(out + idx) = res;
}

extern "C" void kernel_launch(void* const* d_in, const int* in_sizes, int n_in,
                              void* d_out, int out_size, void* d_ws, size_t ws_size,
                              hipStream_t stream) {
    const float* feat = (const float*)d_in[0];
    const int*   mask = (const int*)d_in[1];
    const float* Wq = (const float*)d_in[2];
    const float* bq = (const float*)d_in[3];
    const float* Wk = (const float*)d_in[4];
    const float* bk = (const float*)d_in[5];
    const float* Wv = (const float*)d_in[6];
    const float* bv = (const float*)d_in[7];

    bf16* ws = (bf16*)d_ws;

    convert_in<<<7171, 256, 0, stream>>>(feat, Wq, Wk, Wv, bq, bk, bv, ws);

    dim3 g1(32, 8, 3);
    qkv_gemm<<<g1, 256, 0, stream>>>(ws, ws, mask);

    dim3 g2(2 * NHEAD, SEQ_L / 64, 2);
    attn_kernel<<<g2, 128, 0, stream>>>(ws, ws, mask, (float*)d_out);

    combine<<<4096, 256, 0, stream>>>((float*)d_out, ws);
}